// Round 2
// baseline (101.485 us; speedup 1.0000x reference)
//
#include <hip/hip_runtime.h>
#include <stdint.h>

// BaseRenderer: NeRF-style compositing with per-ray depth sort.
// One wave (64 lanes) per ray, 2 samples per lane (elements 2*lane, 2*lane+1).
// Sort keys are exact 64-bit: (z_bits << 7) | orig_idx  -> stable argsort order.

typedef unsigned long long u64;

__device__ __forceinline__ u64 shfl_xor_u64(u64 v, int mask) {
    int lo = __shfl_xor((int)(uint32_t)v, mask, 64);
    int hi = __shfl_xor((int)(uint32_t)(v >> 32), mask, 64);
    return ((u64)(uint32_t)hi << 32) | (uint32_t)lo;
}

__global__ __launch_bounds__(256) void render_kernel(
    const float* __restrict__ z_vals,
    const float* __restrict__ sigma_vals,
    const float* __restrict__ rgb_vals,
    const float* __restrict__ inst_vals,
    const float* __restrict__ bg_color,
    float* __restrict__ out,
    int N)
{
    constexpr int S = 128;
    constexpr float INF_DIST = 1e10f;
    constexpr float EPS = 1e-10f;

    const int lane = threadIdx.x & 63;
    const int wib  = threadIdx.x >> 6;           // wave in block (4 waves/block)
    int ray = blockIdx.x * 4 + wib;
    if (ray >= N) ray = N - 1;                   // duplicate-safe clamp (no barrier hazard)

    __shared__ float lds_w[4][S];

    const size_t rbase = (size_t)ray * S;

    // ---- coalesced loads: 2 z + 2 sigma per lane ----
    float2 zv = ((const float2*)(z_vals + rbase))[lane];
    float2 sv = ((const float2*)(sigma_vals + rbase))[lane];

    // ---- exact 64-bit sort keys: (z_bits << 7) | original index ----
    // z >= 0 so uint bit order == numeric order; idx low bits = stable tiebreak.
    u64 key0 = ((u64)__float_as_uint(zv.x) << 7) | (u64)(2 * lane);
    u64 key1 = ((u64)__float_as_uint(zv.y) << 7) | (u64)(2 * lane + 1);

    // ---- bitonic sort of 128 keys across the wave ----
    // element index e = 2*lane + r. For step distance j>=2: partner lane = lane ^ (j>>1).
    #pragma unroll
    for (int k = 2; k <= 128; k <<= 1) {
        #pragma unroll
        for (int j = k >> 1; j >= 2; j >>= 1) {
            const int lj = j >> 1;
            u64 p0 = shfl_xor_u64(key0, lj);
            u64 p1 = shfl_xor_u64(key1, lj);
            const bool keepmin = (((lane & lj) == 0) == ((lane & (k >> 1)) == 0));
            u64 mn0 = key0 < p0 ? key0 : p0;
            u64 mx0 = key0 < p0 ? p0 : key0;
            u64 mn1 = key1 < p1 ? key1 : p1;
            u64 mx1 = key1 < p1 ? p1 : key1;
            key0 = keepmin ? mn0 : mx0;
            key1 = keepmin ? mn1 : mx1;
        }
        {   // j == 1: intra-lane compare-exchange of (2*lane, 2*lane+1)
            const bool asc = ((lane & (k >> 1)) == 0);
            u64 lo = key0 < key1 ? key0 : key1;
            u64 hi = key0 < key1 ? key1 : key0;
            key0 = asc ? lo : hi;
            key1 = asc ? hi : lo;
        }
    }

    // ---- unpack sorted z (exact) and original indices ----
    float zs0 = __uint_as_float((uint32_t)(key0 >> 7));
    float zs1 = __uint_as_float((uint32_t)(key1 >> 7));
    int i0 = (int)(key0 & 127u);
    int i1 = (int)(key1 & 127u);

    // ---- gather sigma by original index (variable-lane shuffles from registers) ----
    float s0a = __shfl(sv.x, i0 >> 1, 64);
    float s0b = __shfl(sv.y, i0 >> 1, 64);
    float s1a = __shfl(sv.x, i1 >> 1, 64);
    float s1b = __shfl(sv.y, i1 >> 1, 64);
    float sg0 = (i0 & 1) ? s0b : s0a;
    float sg1 = (i1 & 1) ? s1b : s1a;

    // ---- dists between consecutive sorted samples, last = INF ----
    float znx = __shfl_down(zs0, 1, 64);         // next lane's first element = e+1 for r=1
    float d0 = zs1 - zs0;
    float d1 = (lane == 63) ? INF_DIST : (znx - zs1);

    // ---- alpha / transmittance factors (match reference arithmetic) ----
    float e0 = __expf(-fmaxf(sg0, 0.0f) * d0);
    float e1 = __expf(-fmaxf(sg1, 0.0f) * d1);
    float a0 = 1.0f - e0;
    float a1 = 1.0f - e1;
    float m0 = 1.0f - a0 + EPS;
    float m1 = 1.0f - a1 + EPS;

    // ---- wave-parallel multiply scan for transmittance ----
    float s = m0 * m1;
    #pragma unroll
    for (int d = 1; d < 64; d <<= 1) {
        float t = __shfl_up(s, d, 64);
        if (lane >= d) s *= t;
    }
    float no_hit = __shfl(s, 63, 64);            // product over all S samples
    float excl = __shfl_up(s, 1, 64);
    if (lane == 0) excl = 1.0f;

    float t0 = excl;                              // trans before element 2*lane
    float t1 = excl * m0;                         // trans before element 2*lane+1
    float w0 = a0 * t0;
    float w1 = a1 * t1;

    // ---- w output (sorted order), coalesced float2 ----
    ((float2*)(out + (size_t)7 * N + rbase))[lane] = make_float2(w0, w1);

    // ---- scatter weights back to ORIGINAL sample order via LDS ----
    lds_w[wib][i0] = w0;
    lds_w[wib][i1] = w1;
    __syncthreads();
    float2 wo = ((const float2*)lds_w[wib])[lane];   // weights for samples 2l, 2l+1 (orig order)

    // ---- depth partial in sorted domain (same sum) ----
    float dep = w0 * zs0 + w1 * zs1;

    // ---- coalesced rgb / instance loads in original order (6 floats each per lane) ----
    const float* rp = rgb_vals + rbase * 3 + (size_t)lane * 6;
    float2 r01 = ((const float2*)rp)[0];
    float2 r23 = ((const float2*)rp)[1];
    float2 r45 = ((const float2*)rp)[2];
    const float* ip = inst_vals + rbase * 3 + (size_t)lane * 6;
    float2 q01 = ((const float2*)ip)[0];
    float2 q23 = ((const float2*)ip)[1];
    float2 q45 = ((const float2*)ip)[2];

    // sample 2l   -> (r01.x, r01.y, r23.x);  sample 2l+1 -> (r23.y, r45.x, r45.y)
    float cr = wo.x * r01.x + wo.y * r23.y;
    float cg = wo.x * r01.y + wo.y * r45.x;
    float cb = wo.x * r23.x + wo.y * r45.y;
    float k0 = wo.x * q01.x + wo.y * q23.y;
    float k1 = wo.x * q01.y + wo.y * q45.x;
    float k2 = wo.x * q23.x + wo.y * q45.y;

    // ---- wave reductions (7 values) ----
    #pragma unroll
    for (int d = 1; d < 64; d <<= 1) {
        dep += __shfl_xor(dep, d, 64);
        cr  += __shfl_xor(cr,  d, 64);
        cg  += __shfl_xor(cg,  d, 64);
        cb  += __shfl_xor(cb,  d, 64);
        k0  += __shfl_xor(k0,  d, 64);
        k1  += __shfl_xor(k1,  d, 64);
        k2  += __shfl_xor(k2,  d, 64);
    }

    if (lane == 0) {
        const float* bg = bg_color + (size_t)ray * 3;
        out[(size_t)ray * 3 + 0] = cr + no_hit * bg[0];
        out[(size_t)ray * 3 + 1] = cg + no_hit * bg[1];
        out[(size_t)ray * 3 + 2] = cb + no_hit * bg[2];
        out[(size_t)3 * N + ray] = dep;
        out[(size_t)4 * N + (size_t)ray * 3 + 0] = k0;
        out[(size_t)4 * N + (size_t)ray * 3 + 1] = k1;
        out[(size_t)4 * N + (size_t)ray * 3 + 2] = k2;
    }
}

extern "C" void kernel_launch(void* const* d_in, const int* in_sizes, int n_in,
                              void* d_out, int out_size, void* d_ws, size_t ws_size,
                              hipStream_t stream)
{
    const float* z    = (const float*)d_in[0];
    const float* sg   = (const float*)d_in[1];
    const float* rgb  = (const float*)d_in[2];
    const float* inst = (const float*)d_in[3];
    const float* bg   = (const float*)d_in[4];
    float* out = (float*)d_out;

    const int S = 128;
    int N = in_sizes[0] / S;                 // 65536
    int blocks = (N + 3) / 4;                // 4 rays (waves) per 256-thread block
    render_kernel<<<blocks, 256, 0, stream>>>(z, sg, rgb, inst, bg, out, N);
}

// Round 3
// 55.533 us; speedup vs baseline: 1.8275x; 1.8275x over previous
//
#include <hip/hip_runtime.h>
#include <stdint.h>

// BaseRenderer: NeRF-style compositing with per-ray depth sort.
// One wave (64 lanes) per ray, 2 samples per lane (elements 2*lane, 2*lane+1).
//
// Fast path: JAX uniform*4 z values are exactly m/2^21 (m < 2^23), so a
// 32-bit key (m<<7)|idx gives exact stable argsort order and bit-exact z
// recovery. Runtime-verified per wave; falls back to 64-bit keys otherwise.
// Cross-lane traffic moved off the LDS pipe onto VALU via DPP where possible.

typedef unsigned long long u64;

// ---------------- DPP helpers ----------------
template<int CTRL, int RM>
__device__ __forceinline__ float updpp_f(float oldv, float src) {
    return __uint_as_float((uint32_t)__builtin_amdgcn_update_dpp(
        (int)__float_as_uint(oldv), (int)__float_as_uint(src), CTRL, RM, 0xF, false));
}

template<int CTRL>
__device__ __forceinline__ uint32_t dppmov_u(uint32_t v) {
    return (uint32_t)__builtin_amdgcn_mov_dpp((int)v, CTRL, 0xF, 0xF, true);
}

// 6-op DPP reduction; full-wave total lands in lane 63.
__device__ __forceinline__ float red6(float x) {
    x += updpp_f<0x111, 0xF>(0.0f, x);   // row_shr:1
    x += updpp_f<0x112, 0xF>(0.0f, x);   // row_shr:2
    x += updpp_f<0x114, 0xF>(0.0f, x);   // row_shr:4
    x += updpp_f<0x118, 0xF>(0.0f, x);   // row_shr:8
    x += updpp_f<0x142, 0xA>(0.0f, x);   // row_bcast:15 -> rows 1,3
    x += updpp_f<0x143, 0xC>(0.0f, x);   // row_bcast:31 -> rows 2,3
    return x;
}

// ---------------- 32-bit bitonic sort (fast path) ----------------
template<int LJ>
__device__ __forceinline__ uint32_t xp(uint32_t k) {
    if constexpr (LJ == 1)      return dppmov_u<0xB1>(k);    // quad_perm [1,0,3,2] = xor1
    else if constexpr (LJ == 2) return dppmov_u<0x4E>(k);    // quad_perm [2,3,0,1] = xor2
    else if constexpr (LJ == 8) return dppmov_u<0x128>(k);   // row_ror:8 == xor8 in 16-row
    else return (uint32_t)__shfl_xor((int)k, LJ, 64);        // xor4/16/32 via DS
}

template<int LJ>
__device__ __forceinline__ void cross32(uint32_t& a, uint32_t& b, bool dirbit, int lane) {
    uint32_t pa = xp<LJ>(a);
    uint32_t pb = xp<LJ>(b);
    const bool keepmin = (((lane & LJ) == 0) == dirbit);
    uint32_t mna = a < pa ? a : pa, mxa = a < pa ? pa : a;
    uint32_t mnb = b < pb ? b : pb, mxb = b < pb ? pb : b;
    a = keepmin ? mna : mxa;
    b = keepmin ? mnb : mxb;
    if constexpr (LJ > 1) cross32<LJ / 2>(a, b, dirbit, lane);
}

template<int K>
__device__ __forceinline__ void phase32(uint32_t& a, uint32_t& b, int lane) {
    const bool dirbit = ((lane & (K >> 1)) == 0);
    if constexpr (K >= 4) cross32<K / 4>(a, b, dirbit, lane);
    uint32_t lo = a < b ? a : b, hi = a < b ? b : a;  // intra-lane step (j==1)
    a = dirbit ? lo : hi;
    b = dirbit ? hi : lo;
}

// ---------------- 64-bit fallback sort ----------------
__device__ __forceinline__ u64 shfl_xor_u64(u64 v, int mask) {
    int lo = __shfl_xor((int)(uint32_t)v, mask, 64);
    int hi = __shfl_xor((int)(uint32_t)(v >> 32), mask, 64);
    return ((u64)(uint32_t)hi << 32) | (uint32_t)lo;
}

__global__ __launch_bounds__(256) void render_kernel(
    const float* __restrict__ z_vals,
    const float* __restrict__ sigma_vals,
    const float* __restrict__ rgb_vals,
    const float* __restrict__ inst_vals,
    const float* __restrict__ bg_color,
    float* __restrict__ out,
    int N)
{
    constexpr int S = 128;
    constexpr float INF_DIST = 1e10f;
    constexpr float EPS = 1e-10f;

    const int lane = threadIdx.x & 63;
    const int wib  = threadIdx.x >> 6;           // wave in block (4 waves/block)
    int ray = blockIdx.x * 4 + wib;
    if (ray >= N) ray = N - 1;                   // duplicate-safe clamp

    __shared__ float lds_w[4][S];

    const size_t rbase = (size_t)ray * S;

    // ---- coalesced loads: 2 z + 2 sigma per lane ----
    float2 zv = ((const float2*)(z_vals + rbase))[lane];
    float2 sv = ((const float2*)(sigma_vals + rbase))[lane];

    // ---- dyadic check: z == m / 2^21 with m < 2^23 (exact for JAX uniform*4) ----
    float k0f = zv.x * 2097152.0f;               // * 2^21
    float k1f = zv.y * 2097152.0f;
    uint32_t m0i = (uint32_t)k0f;
    uint32_t m1i = (uint32_t)k1f;
    bool exact = (k0f == (float)m0i) && (k1f == (float)m1i) &&
                 (m0i < (1u << 23)) && (m1i < (1u << 23));

    uint32_t i0, i1;
    float zs0, zs1;

    if (__ballot(exact) == ~0ull) {
        // ---- fast: 32-bit keys (m<<7)|idx, exact stable order ----
        uint32_t a = (m0i << 7) | (uint32_t)(2 * lane);
        uint32_t b = (m1i << 7) | (uint32_t)(2 * lane + 1);
        phase32<2>(a, b, lane);
        phase32<4>(a, b, lane);
        phase32<8>(a, b, lane);
        phase32<16>(a, b, lane);
        phase32<32>(a, b, lane);
        phase32<64>(a, b, lane);
        phase32<128>(a, b, lane);
        i0 = a & 127u;
        i1 = b & 127u;
        zs0 = (float)(a >> 7) * 0x1p-21f;        // bit-exact z recovery
        zs1 = (float)(b >> 7) * 0x1p-21f;
    } else {
        // ---- fallback: exact 64-bit keys (z_bits<<7)|idx ----
        u64 a = ((u64)__float_as_uint(zv.x) << 7) | (u64)(2 * lane);
        u64 b = ((u64)__float_as_uint(zv.y) << 7) | (u64)(2 * lane + 1);
        #pragma unroll
        for (int k = 2; k <= 128; k <<= 1) {
            #pragma unroll
            for (int j = k >> 1; j >= 2; j >>= 1) {
                const int lj = j >> 1;
                u64 pa = shfl_xor_u64(a, lj);
                u64 pb = shfl_xor_u64(b, lj);
                const bool keepmin = (((lane & lj) == 0) == ((lane & (k >> 1)) == 0));
                u64 mna = a < pa ? a : pa, mxa = a < pa ? pa : a;
                u64 mnb = b < pb ? b : pb, mxb = b < pb ? pb : b;
                a = keepmin ? mna : mxa;
                b = keepmin ? mnb : mxb;
            }
            const bool asc = ((lane & (k >> 1)) == 0);
            u64 lo = a < b ? a : b, hi = a < b ? b : a;
            a = asc ? lo : hi;
            b = asc ? hi : lo;
        }
        i0 = (int)(a & 127u);
        i1 = (int)(b & 127u);
        zs0 = __uint_as_float((uint32_t)(a >> 7));
        zs1 = __uint_as_float((uint32_t)(b >> 7));
    }

    // ---- gather sigma by original index (variable-lane shuffles) ----
    float s0a = __shfl(sv.x, (int)(i0 >> 1), 64);
    float s0b = __shfl(sv.y, (int)(i0 >> 1), 64);
    float s1a = __shfl(sv.x, (int)(i1 >> 1), 64);
    float s1b = __shfl(sv.y, (int)(i1 >> 1), 64);
    float sg0 = (i0 & 1) ? s0b : s0a;
    float sg1 = (i1 & 1) ? s1b : s1a;

    // ---- dists; lane63 boundary handled by DPP old=INF (1e10 - z rounds to 1e10 exactly) ----
    float znx = updpp_f<0x130, 0xF>(INF_DIST, zs0);   // wave_shl:1 -> lane i gets zs0[i+1]
    float d0 = zs1 - zs0;
    float d1 = znx - zs1;

    // ---- alpha / transmittance factors (match reference arithmetic) ----
    float e0 = __expf(-fmaxf(sg0, 0.0f) * d0);
    float e1 = __expf(-fmaxf(sg1, 0.0f) * d1);
    float a0 = 1.0f - e0;
    float a1 = 1.0f - e1;
    float m0 = 1.0f - a0 + EPS;
    float m1 = 1.0f - a1 + EPS;

    // ---- DPP multiply-scan (inclusive), identity 1.0 ----
    float s = m0 * m1;
    s *= updpp_f<0x111, 0xF>(1.0f, s);   // row_shr:1
    s *= updpp_f<0x112, 0xF>(1.0f, s);   // row_shr:2
    s *= updpp_f<0x114, 0xF>(1.0f, s);   // row_shr:4
    s *= updpp_f<0x118, 0xF>(1.0f, s);   // row_shr:8
    s *= updpp_f<0x142, 0xA>(1.0f, s);   // row_bcast:15
    s *= updpp_f<0x143, 0xC>(1.0f, s);   // row_bcast:31
    // s = inclusive product through this lane's 2 samples; lane63 = no_hit.

    float excl = updpp_f<0x138, 0xF>(1.0f, s);        // wave_shr:1, lane0 -> 1.0

    float t0 = excl;                      // trans before element 2*lane
    float t1 = excl * m0;                 // trans before element 2*lane+1
    float w0 = a0 * t0;
    float w1 = a1 * t1;

    // ---- w output (sorted order), coalesced float2 ----
    ((float2*)(out + (size_t)7 * N + rbase))[lane] = make_float2(w0, w1);

    // ---- scatter weights back to ORIGINAL sample order via LDS ----
    lds_w[wib][i0] = w0;
    lds_w[wib][i1] = w1;
    __syncthreads();
    float2 wo = ((const float2*)lds_w[wib])[lane];

    // ---- depth partial in sorted domain (same sum) ----
    float dep = w0 * zs0 + w1 * zs1;

    // ---- coalesced rgb / instance loads in original order ----
    const float* rp = rgb_vals + rbase * 3 + (size_t)lane * 6;
    float2 r01 = ((const float2*)rp)[0];
    float2 r23 = ((const float2*)rp)[1];
    float2 r45 = ((const float2*)rp)[2];
    const float* ip = inst_vals + rbase * 3 + (size_t)lane * 6;
    float2 q01 = ((const float2*)ip)[0];
    float2 q23 = ((const float2*)ip)[1];
    float2 q45 = ((const float2*)ip)[2];

    // sample 2l -> (r01.x, r01.y, r23.x); sample 2l+1 -> (r23.y, r45.x, r45.y)
    float cr = wo.x * r01.x + wo.y * r23.y;
    float cg = wo.x * r01.y + wo.y * r45.x;
    float cb = wo.x * r23.x + wo.y * r45.y;
    float k0 = wo.x * q01.x + wo.y * q23.y;
    float k1 = wo.x * q01.y + wo.y * q45.x;
    float k2 = wo.x * q23.x + wo.y * q45.y;

    // ---- DPP reductions; totals land in lane 63 (which also holds no_hit = s) ----
    dep = red6(dep);
    cr  = red6(cr);
    cg  = red6(cg);
    cb  = red6(cb);
    k0  = red6(k0);
    k1  = red6(k1);
    k2  = red6(k2);

    if (lane == 63) {
        float no_hit = s;                 // inclusive product over all S samples
        const float* bg = bg_color + (size_t)ray * 3;
        out[(size_t)ray * 3 + 0] = cr + no_hit * bg[0];
        out[(size_t)ray * 3 + 1] = cg + no_hit * bg[1];
        out[(size_t)ray * 3 + 2] = cb + no_hit * bg[2];
        out[(size_t)3 * N + ray] = dep;
        out[(size_t)4 * N + (size_t)ray * 3 + 0] = k0;
        out[(size_t)4 * N + (size_t)ray * 3 + 1] = k1;
        out[(size_t)4 * N + (size_t)ray * 3 + 2] = k2;
    }
}

extern "C" void kernel_launch(void* const* d_in, const int* in_sizes, int n_in,
                              void* d_out, int out_size, void* d_ws, size_t ws_size,
                              hipStream_t stream)
{
    const float* z    = (const float*)d_in[0];
    const float* sg   = (const float*)d_in[1];
    const float* rgb  = (const float*)d_in[2];
    const float* inst = (const float*)d_in[3];
    const float* bg   = (const float*)d_in[4];
    float* out = (float*)d_out;

    const int S = 128;
    int N = in_sizes[0] / S;                 // 65536
    int blocks = (N + 3) / 4;                // 4 rays (waves) per 256-thread block
    render_kernel<<<blocks, 256, 0, stream>>>(z, sg, rgb, inst, bg, out, N);
}

// Round 4
// 49.476 us; speedup vs baseline: 2.0512x; 1.1224x over previous
//
#include <hip/hip_runtime.h>
#include <stdint.h>

// BaseRenderer: NeRF-style compositing with per-ray depth sort.
// One wave (64 lanes) per ray, 2 samples per lane (elements 2*lane, 2*lane+1).
//
// Round 4: hide HBM latency of rgb/inst under the sort via global_load_lds
// staging (drained by the existing __syncthreads); cheaper bitonic selects;
// w store moved after the barrier + nontemporal.

typedef unsigned long long u64;

// ---------------- DPP helpers ----------------
template<int CTRL, int RM>
__device__ __forceinline__ float updpp_f(float oldv, float src) {
    return __uint_as_float((uint32_t)__builtin_amdgcn_update_dpp(
        (int)__float_as_uint(oldv), (int)__float_as_uint(src), CTRL, RM, 0xF, false));
}

template<int CTRL>
__device__ __forceinline__ uint32_t dppmov_u(uint32_t v) {
    return (uint32_t)__builtin_amdgcn_mov_dpp((int)v, CTRL, 0xF, 0xF, true);
}

// 6-op DPP reduction; full-wave total lands in lane 63.
__device__ __forceinline__ float red6(float x) {
    x += updpp_f<0x111, 0xF>(0.0f, x);   // row_shr:1
    x += updpp_f<0x112, 0xF>(0.0f, x);   // row_shr:2
    x += updpp_f<0x114, 0xF>(0.0f, x);   // row_shr:4
    x += updpp_f<0x118, 0xF>(0.0f, x);   // row_shr:8
    x += updpp_f<0x142, 0xA>(0.0f, x);   // row_bcast:15 -> rows 1,3
    x += updpp_f<0x143, 0xC>(0.0f, x);   // row_bcast:31 -> rows 2,3
    return x;
}

// ---------------- 32-bit bitonic sort (fast path) ----------------
template<int LJ>
__device__ __forceinline__ uint32_t xp(uint32_t k) {
    if constexpr (LJ == 1)      return dppmov_u<0xB1>(k);    // quad_perm [1,0,3,2] = xor1
    else if constexpr (LJ == 2) return dppmov_u<0x4E>(k);    // quad_perm [2,3,0,1] = xor2
    else if constexpr (LJ == 8) return dppmov_u<0x128>(k);   // row_ror:8 == xor8 in 16-row
    else return (uint32_t)__shfl_xor((int)k, LJ, 64);        // xor4/16/32 via DS
}

template<int LJ>
__device__ __forceinline__ void cross32(uint32_t& a, uint32_t& b, bool dirbit, int lane) {
    uint32_t pa = xp<LJ>(a);
    uint32_t pb = xp<LJ>(b);
    const bool keepmin = (((lane & LJ) == 0) == dirbit);
    // keepmin -> want min(a,pa): take pa iff pa<a.  !keepmin -> max: take pa iff pa>=a.
    // Keys are unique, so ties never occur.
    a = (((pa < a)) == keepmin) ? pa : a;
    b = (((pb < b)) == keepmin) ? pb : b;
    if constexpr (LJ > 1) cross32<LJ / 2>(a, b, dirbit, lane);
}

template<int K>
__device__ __forceinline__ void phase32(uint32_t& a, uint32_t& b, int lane) {
    const bool dirbit = ((lane & (K >> 1)) == 0);
    if constexpr (K >= 4) cross32<K / 4>(a, b, dirbit, lane);
    // intra-lane step (j==1): swap iff (b<a)==dirbit  (asc: b<a; desc: a<b)
    const bool sw = ((b < a) == dirbit);
    uint32_t t = a;
    a = sw ? b : a;
    b = sw ? t : b;
}

// ---------------- 64-bit fallback sort ----------------
__device__ __forceinline__ u64 shfl_xor_u64(u64 v, int mask) {
    int lo = __shfl_xor((int)(uint32_t)v, mask, 64);
    int hi = __shfl_xor((int)(uint32_t)(v >> 32), mask, 64);
    return ((u64)(uint32_t)hi << 32) | (uint32_t)lo;
}

#define GLL16(gsrc, ldst) __builtin_amdgcn_global_load_lds(                    \
    (const __attribute__((address_space(1))) void*)(gsrc),                     \
    (__attribute__((address_space(3))) void*)(ldst), 16, 0, 0)

__global__ __launch_bounds__(256) void render_kernel(
    const float* __restrict__ z_vals,
    const float* __restrict__ sigma_vals,
    const float* __restrict__ rgb_vals,
    const float* __restrict__ inst_vals,
    const float* __restrict__ bg_color,
    float* __restrict__ out,
    int N)
{
    constexpr int S = 128;
    constexpr float INF_DIST = 1e10f;
    constexpr float EPS = 1e-10f;

    const int lane = threadIdx.x & 63;
    const int wib  = threadIdx.x >> 6;           // wave in block (4 waves/block)
    int ray = blockIdx.x * 4 + wib;
    if (ray >= N) ray = N - 1;                   // duplicate-safe clamp

    __shared__ float lds_w[4][S];                //  2 KiB
    __shared__ float lds_rgb[4][S * 3];          //  6 KiB
    __shared__ float lds_inst[4][S * 3];         //  6 KiB

    const size_t rbase = (size_t)ray * S;

    // ---- coalesced VGPR loads: 2 z + 2 sigma per lane (sort needs these first) ----
    float2 zv = ((const float2*)(z_vals + rbase))[lane];
    float2 sv = ((const float2*)(sigma_vals + rbase))[lane];

    // ---- async staging: this wave's rgb (1536B) + inst (1536B) into LDS ----
    // Issued now, drained by the __syncthreads after the sort -> latency hidden.
    {
        const char* rsrc = (const char*)(rgb_vals  + rbase * 3);
        const char* isrc = (const char*)(inst_vals + rbase * 3);
        char* rdst = (char*)&lds_rgb[wib][0];
        char* idst = (char*)&lds_inst[wib][0];
        GLL16(rsrc + (size_t)lane * 16, rdst);             // bytes [0,1024)
        GLL16(isrc + (size_t)lane * 16, idst);
        if (lane < 32) {
            GLL16(rsrc + 1024 + (size_t)lane * 16, rdst + 1024);   // bytes [1024,1536)
            GLL16(isrc + 1024 + (size_t)lane * 16, idst + 1024);
        }
    }

    // ---- bg_color early (only lane 63 consumes it, in the epilogue) ----
    float bg0 = 0.0f, bg1 = 0.0f, bg2 = 0.0f;
    if (lane == 63) {
        const float* bg = bg_color + (size_t)ray * 3;
        bg0 = bg[0]; bg1 = bg[1]; bg2 = bg[2];
    }

    // ---- dyadic check: z == m / 2^21 with m < 2^23 (exact for JAX uniform*4) ----
    float k0f = zv.x * 2097152.0f;               // * 2^21
    float k1f = zv.y * 2097152.0f;
    uint32_t m0i = (uint32_t)k0f;
    uint32_t m1i = (uint32_t)k1f;
    bool exact = (k0f == (float)m0i) && (k1f == (float)m1i) &&
                 (m0i < (1u << 23)) && (m1i < (1u << 23));

    uint32_t i0, i1;
    float zs0, zs1;

    if (__ballot(exact) == ~0ull) {
        // ---- fast: 32-bit keys (m<<7)|idx, exact stable order ----
        uint32_t a = (m0i << 7) | (uint32_t)(2 * lane);
        uint32_t b = (m1i << 7) | (uint32_t)(2 * lane + 1);
        phase32<2>(a, b, lane);
        phase32<4>(a, b, lane);
        phase32<8>(a, b, lane);
        phase32<16>(a, b, lane);
        phase32<32>(a, b, lane);
        phase32<64>(a, b, lane);
        phase32<128>(a, b, lane);
        i0 = a & 127u;
        i1 = b & 127u;
        zs0 = (float)(a >> 7) * 0x1p-21f;        // bit-exact z recovery
        zs1 = (float)(b >> 7) * 0x1p-21f;
    } else {
        // ---- fallback: exact 64-bit keys (z_bits<<7)|idx ----
        u64 a = ((u64)__float_as_uint(zv.x) << 7) | (u64)(2 * lane);
        u64 b = ((u64)__float_as_uint(zv.y) << 7) | (u64)(2 * lane + 1);
        #pragma unroll
        for (int k = 2; k <= 128; k <<= 1) {
            #pragma unroll
            for (int j = k >> 1; j >= 2; j >>= 1) {
                const int lj = j >> 1;
                u64 pa = shfl_xor_u64(a, lj);
                u64 pb = shfl_xor_u64(b, lj);
                const bool keepmin = (((lane & lj) == 0) == ((lane & (k >> 1)) == 0));
                a = ((pa < a) == keepmin) ? pa : a;
                b = ((pb < b) == keepmin) ? pb : b;
            }
            const bool asc = ((lane & (k >> 1)) == 0);
            const bool sw = ((b < a) == asc);
            u64 t = a;
            a = sw ? b : a;
            b = sw ? t : b;
        }
        i0 = (uint32_t)(a & 127u);
        i1 = (uint32_t)(b & 127u);
        zs0 = __uint_as_float((uint32_t)(a >> 7));
        zs1 = __uint_as_float((uint32_t)(b >> 7));
    }

    // ---- gather sigma by original index (variable-lane shuffles) ----
    float s0a = __shfl(sv.x, (int)(i0 >> 1), 64);
    float s0b = __shfl(sv.y, (int)(i0 >> 1), 64);
    float s1a = __shfl(sv.x, (int)(i1 >> 1), 64);
    float s1b = __shfl(sv.y, (int)(i1 >> 1), 64);
    float sg0 = (i0 & 1) ? s0b : s0a;
    float sg1 = (i1 & 1) ? s1b : s1a;

    // ---- dists; lane63 boundary via DPP old=INF (1e10 - z rounds to 1e10) ----
    float znx = updpp_f<0x130, 0xF>(INF_DIST, zs0);   // wave_shl:1 -> lane i gets zs0[i+1]
    float d0 = zs1 - zs0;
    float d1 = znx - zs1;

    // ---- alpha / transmittance factors (match reference arithmetic) ----
    float e0 = __expf(-fmaxf(sg0, 0.0f) * d0);
    float e1 = __expf(-fmaxf(sg1, 0.0f) * d1);
    float a0 = 1.0f - e0;
    float a1 = 1.0f - e1;
    float m0 = 1.0f - a0 + EPS;
    float m1 = 1.0f - a1 + EPS;

    // ---- DPP multiply-scan (inclusive), identity 1.0 ----
    float s = m0 * m1;
    s *= updpp_f<0x111, 0xF>(1.0f, s);   // row_shr:1
    s *= updpp_f<0x112, 0xF>(1.0f, s);   // row_shr:2
    s *= updpp_f<0x114, 0xF>(1.0f, s);   // row_shr:4
    s *= updpp_f<0x118, 0xF>(1.0f, s);   // row_shr:8
    s *= updpp_f<0x142, 0xA>(1.0f, s);   // row_bcast:15
    s *= updpp_f<0x143, 0xC>(1.0f, s);   // row_bcast:31
    // s = inclusive product through this lane's 2 samples; lane63 = no_hit.

    float excl = updpp_f<0x138, 0xF>(1.0f, s);        // wave_shr:1, lane0 -> 1.0

    float t0 = excl;                      // trans before element 2*lane
    float t1 = excl * m0;                 // trans before element 2*lane+1
    float w0 = a0 * t0;
    float w1 = a1 * t1;

    // ---- scatter weights back to ORIGINAL sample order via LDS ----
    lds_w[wib][i0] = w0;
    lds_w[wib][i1] = w1;
    __syncthreads();                      // also drains the gll staging (vmcnt 0)

    // ---- w output (sorted order), nontemporal 8B store, after the barrier ----
    {
        u64 wbits = ((u64)__float_as_uint(w1) << 32) | (u64)__float_as_uint(w0);
        __builtin_nontemporal_store(wbits, (u64*)(out + (size_t)7 * N + rbase) + lane);
    }

    float2 wo = ((const float2*)lds_w[wib])[lane];

    // ---- depth partial in sorted domain (same sum) ----
    float dep = w0 * zs0 + w1 * zs1;

    // ---- rgb / instance from LDS (staged), original order: 6 floats each ----
    const float2* rp2 = (const float2*)&lds_rgb[wib][lane * 6];
    float2 r01 = rp2[0];
    float2 r23 = rp2[1];
    float2 r45 = rp2[2];
    const float2* ip2 = (const float2*)&lds_inst[wib][lane * 6];
    float2 q01 = ip2[0];
    float2 q23 = ip2[1];
    float2 q45 = ip2[2];

    // sample 2l -> (r01.x, r01.y, r23.x); sample 2l+1 -> (r23.y, r45.x, r45.y)
    float cr = wo.x * r01.x + wo.y * r23.y;
    float cg = wo.x * r01.y + wo.y * r45.x;
    float cb = wo.x * r23.x + wo.y * r45.y;
    float k0 = wo.x * q01.x + wo.y * q23.y;
    float k1 = wo.x * q01.y + wo.y * q45.x;
    float k2 = wo.x * q23.x + wo.y * q45.y;

    // ---- DPP reductions; totals land in lane 63 (which also holds no_hit = s) ----
    dep = red6(dep);
    cr  = red6(cr);
    cg  = red6(cg);
    cb  = red6(cb);
    k0  = red6(k0);
    k1  = red6(k1);
    k2  = red6(k2);

    if (lane == 63) {
        float no_hit = s;                 // inclusive product over all S samples
        out[(size_t)ray * 3 + 0] = cr + no_hit * bg0;
        out[(size_t)ray * 3 + 1] = cg + no_hit * bg1;
        out[(size_t)ray * 3 + 2] = cb + no_hit * bg2;
        out[(size_t)3 * N + ray] = dep;
        out[(size_t)4 * N + (size_t)ray * 3 + 0] = k0;
        out[(size_t)4 * N + (size_t)ray * 3 + 1] = k1;
        out[(size_t)4 * N + (size_t)ray * 3 + 2] = k2;
    }
}

extern "C" void kernel_launch(void* const* d_in, const int* in_sizes, int n_in,
                              void* d_out, int out_size, void* d_ws, size_t ws_size,
                              hipStream_t stream)
{
    const float* z    = (const float*)d_in[0];
    const float* sg   = (const float*)d_in[1];
    const float* rgb  = (const float*)d_in[2];
    const float* inst = (const float*)d_in[3];
    const float* bg   = (const float*)d_in[4];
    float* out = (float*)d_out;

    const int S = 128;
    int N = in_sizes[0] / S;                 // 65536
    int blocks = (N + 3) / 4;                // 4 rays (waves) per 256-thread block
    render_kernel<<<blocks, 256, 0, stream>>>(z, sg, rgb, inst, bg, out, N);
}